// Round 16
// baseline (1178.820 us; speedup 1.0000x reference)
//
#include <hip/hip_runtime.h>
#include <math.h>

#define BATCH 32768
#define ISZ   256
#define HSZ   512
#define KC    768   // cell GEMM K = ISZ + HSZ

typedef __attribute__((ext_vector_type(8))) short bf16x8;
typedef __attribute__((ext_vector_type(4))) float f32x4;

// bf16 activation / weight buffers (static to avoid ws_size dependence)
static __device__ unsigned short g_xbf[(size_t)BATCH * ISZ];   // x in bf16
static __device__ unsigned short g_ha [(size_t)BATCH * HSZ];   // h0 (bf16)
static __device__ unsigned short g_hb [(size_t)BATCH * HSZ];   // h1 (bf16)
static __device__ float          g_h2f[(size_t)BATCH * HSZ];   // new_h fp32
static __device__ unsigned short g_Wc [2048 * KC];             // [Wih | Whh] bf16 [2048][768]
static __device__ unsigned short g_W1p[HSZ * HSZ];             // W1 in MFMA-fragment order
static __device__ unsigned short g_W2p[HSZ * HSZ];             // W2 in MFMA-fragment order

__device__ __forceinline__ unsigned short f2bf(float f) {
    unsigned int u = __float_as_uint(f);
    u += 0x7fff + ((u >> 16) & 1);   // RNE
    return (unsigned short)(u >> 16);
}
__device__ __forceinline__ float bf2f(unsigned short s) {
    return __uint_as_float((unsigned int)s << 16);
}
__device__ __forceinline__ float fsigm(float x) { return 1.0f / (1.0f + __expf(-x)); }
__device__ __forceinline__ float ftanh(float x) { return 1.0f - 2.0f / (__expf(2.0f * x) + 1.0f); }

__device__ __forceinline__ void gload16(const void* g, void* l) {
    __builtin_amdgcn_global_load_lds(
        (const __attribute__((address_space(1))) unsigned int*)g,
        (__attribute__((address_space(3))) unsigned int*)l, 16, 0, 0);
}

// ---------------------------------------------------------------------------
// fp32 -> bf16 conversion (float4-vectorized, row restride for Wih|Whh concat)
// DST: 0=g_xbf 1=g_ha 2=g_Wc
// ---------------------------------------------------------------------------
template <int DST>
__global__ __launch_bounds__(256) void conv_kernel(
    const float* __restrict__ src, int nv, int w4shift, int dstride, int doff)
{
    unsigned short* __restrict__ dst = DST == 0 ? g_xbf : DST == 1 ? g_ha : g_Wc;
    int i = blockIdx.x * 256 + threadIdx.x;
    const int gs = gridDim.x * 256;
    for (; i < nv; i += gs) {
        const int r = i >> w4shift;
        const int c = i & ((1 << w4shift) - 1);
        const float4 v = ((const float4*)src)[i];
        ushort4 o;
        o.x = f2bf(v.x); o.y = f2bf(v.y); o.z = f2bf(v.z); o.w = f2bf(v.w);
        *(ushort4*)&dst[(size_t)r * dstride + doff + c * 4] = o;
    }
}

// ---------------------------------------------------------------------------
// W1/W2 -> MFMA fragment order: chunk c = fb*1024 + st*64 + lq*16 + l15:
//   W'[c*8 + e] = W[fb*16+l15][st*32 + lq*8 + e]
// Fragment (fb, st) for lane l contiguous at W' + (fb*16+st)*512 + l*8 (1KB).
// ---------------------------------------------------------------------------
template <int DST>   // 0 -> g_W1p, 1 -> g_W2p
__global__ __launch_bounds__(256) void conv_fragW(const float* __restrict__ src)
{
    unsigned short* __restrict__ dst = DST == 0 ? g_W1p : g_W2p;
    const int c = blockIdx.x * 256 + threadIdx.x;   // 32768 chunks
    const int l15 = c & 15, lq = (c >> 4) & 3, st = (c >> 6) & 15, fb = c >> 10;
    const int n = fb * 16 + l15;
    const int k = st * 32 + lq * 8;
    const float4 v0 = *(const float4*)&src[(size_t)n * HSZ + k];
    const float4 v1 = *(const float4*)&src[(size_t)n * HSZ + k + 4];
    unsigned short o[8] = {f2bf(v0.x), f2bf(v0.y), f2bf(v0.z), f2bf(v0.w),
                           f2bf(v1.x), f2bf(v1.y), f2bf(v1.z), f2bf(v1.w)};
    *(bf16x8*)&dst[(size_t)c * 8] = *(bf16x8*)o;
}

// ---------------------------------------------------------------------------
// LSTM cell MFMA GEMM, SINGLE-buffered (m97-style, R15-proven): 128x128 tile,
// BK=64, 4 waves, 32KB LDS -> high occupancy, cross-block implicit overlap.
// 1D grid, bijective XCD swizzle, n-chunk fastest (A-panel L2 reuse).
// MODE 0: h1 -> g_hb (bf16).  MODE 1: h2 -> g_h2f (fp32).
// ---------------------------------------------------------------------------
template <int MODE>
__global__ __launch_bounds__(256) void cell_kernel(
    const float* __restrict__ bih, const float* __restrict__ bhh,
    const float* __restrict__ c_in, float* __restrict__ c_out)
{
    constexpr int NKT = KC / 64;   // 12
    constexpr int NCH = 16;

    __shared__ __align__(16) unsigned short As[128 * 64];
    __shared__ __align__(16) unsigned short Bs[128 * 64];

    const int orig = blockIdx.x;
    const int q = gridDim.x >> 3;
    const int wg = (orig & 7) * q + (orig >> 3);
    const int nbc = wg % NCH;
    const int mBase = (wg / NCH) * 128;

    const int tid  = threadIdx.x;
    const int lane = tid & 63;
    const int wid  = tid >> 6;
    const int wr   = wid >> 1, wc = wid & 1;
    const int l15  = lane & 15, lq = lane >> 4;

    const unsigned short* __restrict__ Ah = (MODE == 0) ? g_ha : g_hb;

    const int arow = tid >> 3, ch = tid & 7;
    int bgrow[4];
#pragma unroll
    for (int j = 0; j < 4; ++j) {
        const int vr = j * 32 + arow;
        const int g    = (vr >> 4) & 3;
        const int jcol = nbc * 32 + (vr >> 6) * 16 + (vr & 15);
        bgrow[j] = g * 512 + jcol;
    }

    f32x4 acc[4][4];
#pragma unroll
    for (int fm = 0; fm < 4; ++fm)
#pragma unroll
        for (int fn = 0; fn < 4; ++fn) acc[fm][fn] = (f32x4){0.f, 0.f, 0.f, 0.f};

    for (int kt = 0; kt < NKT; ++kt) {
        const int k0 = kt * 64;
#pragma unroll
        for (int j = 0; j < 4; ++j) {
            const int row = j * 32 + arow;
            const unsigned short* ga = (k0 < 256)
                ? g_xbf + (size_t)(mBase + row) * ISZ + (k0       + ch * 8)
                : Ah    + (size_t)(mBase + row) * HSZ + (k0 - 256 + ch * 8);
            gload16(ga, (char*)As + j * 4096 + wid * 1024);
            const unsigned short* gb = g_Wc + (size_t)bgrow[j] * KC + k0 + ch * 8;
            gload16(gb, (char*)Bs + j * 4096 + wid * 1024);
        }
        __syncthreads();
#pragma unroll
        for (int kk = 0; kk < 2; ++kk) {
            bf16x8 a[4], b[4];
#pragma unroll
            for (int f = 0; f < 4; ++f) {
                const int rowA = wr * 64 + f * 16 + l15;
                a[f] = *(const bf16x8*)((const char*)As + rowA * 128 + kk * 64 + lq * 16);
                const int rowB = wc * 64 + f * 16 + l15;
                b[f] = *(const bf16x8*)((const char*)Bs + rowB * 128 + kk * 64 + lq * 16);
            }
#pragma unroll
            for (int fm = 0; fm < 4; ++fm)
#pragma unroll
                for (int fn = 0; fn < 4; ++fn)
                    acc[fm][fn] = __builtin_amdgcn_mfma_f32_16x16x32_bf16(
                        a[fm], b[fn], acc[fm][fn], 0, 0, 0);
        }
        __syncthreads();
    }

    const int j = nbc * 32 + wc * 16 + l15;
    float bsum[4];
#pragma unroll
    for (int g = 0; g < 4; ++g) bsum[g] = bih[g * 512 + j] + bhh[g * 512 + j];
#pragma unroll
    for (int fm = 0; fm < 4; ++fm) {
#pragma unroll
        for (int r = 0; r < 4; ++r) {
            const int m = mBase + wr * 64 + fm * 16 + lq * 4 + r;
            const size_t idx = (size_t)m * HSZ + j;
            const float ig = fsigm(acc[fm][0][r] + bsum[0]);
            const float fg = fsigm(acc[fm][1][r] + bsum[1]);
            const float gg = ftanh(acc[fm][2][r] + bsum[2]);
            const float og = fsigm(acc[fm][3][r] + bsum[3]);
            const float cnew = fg * c_in[idx] + ig * gg;
            const float hnew = og * ftanh(cnew);
            c_out[idx] = cnew;
            if constexpr (MODE == 0) g_hb[idx] = f2bf(hnew);
            else                     g_h2f[idx] = hnew;
        }
    }
}

// ---------------------------------------------------------------------------
// Fully-fused RK4, v12 = R11/R15 structure with two coupled changes:
// (1) W register-prefetch deepened to distance-2 full-steps: 3 static buffers
//     b[3] (48 VGPRs), fully-unrolled K-loop with compile-time %3 rotation +
//     one sched_barrier(0) per step (keeps the 8-MFMA cluster intact — the
//     R14 mistake was splitting it).
// (2) rk accumulator evicted from registers into out_ht (fp32, thread-owned):
//     s0 write kv; s1/s2 += 2kv; s3 final = h2 + dt/6*(acc + kv). Frees the
//     32 VGPRs that pay for (1). Live ~118 <= 128 -> no spill.
// Block = 32 rows x 512 threads (8 waves), wave owns 32x64.
// LDS: sU 32KB (htmp/u, XOR-swizzled) + sH 32KB (h2 bf16).
// ---------------------------------------------------------------------------
__global__ __launch_bounds__(512, 1) void rk_fused_kernel(
    const float* __restrict__ ts, const float* __restrict__ b1,
    const float* __restrict__ b2, float* __restrict__ out_ht)
{
    __shared__ __align__(16) unsigned short sU[32 * 512];   // 32 KB
    __shared__ __align__(16) unsigned short sH[32 * 512];   // 32 KB

    const int tid = threadIdx.x, lane = tid & 63;
    const int w = tid >> 6;                  // wave -> 64-col chunk
    const int l15 = lane & 15, lq = lane >> 4;
    const int nb = w * 64;
    const int m0 = blockIdx.x * 32;

    float b1v[4], b2v[4];
#pragma unroll
    for (int fn = 0; fn < 4; ++fn) {
        b1v[fn] = b1[nb + fn * 16 + l15];
        b2v[fn] = b2[nb + fn * 16 + l15];
    }

    // init: coalesced float4 read of h2, seed sU (htmp) and sH (h2 bf16)
    {
        const float4* __restrict__ src = (const float4*)(g_h2f + (size_t)m0 * HSZ);
#pragma unroll
        for (int i = 0; i < 8; ++i) {
            const int flat = i * 512 + tid;       // float4 index in 32x128
            const int row = flat >> 7;
            const int c4 = flat & 127;
            const float4 v = src[flat];
            ushort4 o;
            o.x = f2bf(v.x); o.y = f2bf(v.y); o.z = f2bf(v.z); o.w = f2bf(v.w);
            const int off = row * 1024 + ((c4 * 8) ^ ((row & 7) << 4));
            *(ushort4*)((char*)sU + off) = o;
            *(ushort4*)((char*)sH + off) = o;
        }
    }
    __syncthreads();

    // fragment loaders
    auto loadB = [&](bf16x8 (&bb)[4], const unsigned short* __restrict__ Wp, int st) {
#pragma unroll
        for (int f = 0; f < 4; ++f)
            bb[f] = *(const bf16x8*)(Wp + (size_t)(((w * 4 + f) * 16 + st) * 512 + lane * 8));
    };
    auto loadA = [&](bf16x8 (&aa)[2], int st) {
#pragma unroll
        for (int f = 0; f < 2; ++f) {
            const int row = f * 16 + l15;
            aa[f] = *(const bf16x8*)((const char*)sU + row * 1024 +
                                     ((st * 64 + lq * 16) ^ ((l15 & 7) << 4)));
        }
    };

    auto do_gemm = [&](const unsigned short* __restrict__ Wp, f32x4 (&gacc)[2][4]) {
#pragma unroll
        for (int fm = 0; fm < 2; ++fm)
#pragma unroll
            for (int fn = 0; fn < 4; ++fn) gacc[fm][fn] = (f32x4){0.f, 0.f, 0.f, 0.f};
        bf16x8 b[3][4], a[2];
        loadB(b[0], Wp, 0);
        loadB(b[1], Wp, 1);
#pragma unroll
        for (int st = 0; st < 16; ++st) {
            if (st + 2 < 16) loadB(b[(st + 2) % 3], Wp, st + 2);
            loadA(a, st);
#pragma unroll
            for (int fm = 0; fm < 2; ++fm)
#pragma unroll
                for (int fn = 0; fn < 4; ++fn)
                    gacc[fm][fn] = __builtin_amdgcn_mfma_f32_16x16x32_bf16(
                        a[fm], b[st % 3][fn], gacc[fm][fn], 0, 0, 0);
            __builtin_amdgcn_sched_barrier(0);
        }
    };

#pragma unroll 1
    for (int s = 0; s < 4; ++s) {
        f32x4 gacc[2][4];
        // GEMM1: u = tanh(htmp @ W1^T + b1)
        do_gemm(g_W1p, gacc);
        __syncthreads();                      // htmp reads complete
#pragma unroll
        for (int fm = 0; fm < 2; ++fm)
#pragma unroll
            for (int fn = 0; fn < 4; ++fn)
#pragma unroll
                for (int r = 0; r < 4; ++r) {
                    const int row = fm * 16 + lq * 4 + r;
                    const int col = nb + fn * 16 + l15;
                    *(unsigned short*)((char*)sU + row * 1024 +
                                       ((col * 2) ^ ((row & 7) << 4))) =
                        f2bf(ftanh(gacc[fm][fn][r] + b1v[fn]));
                }
        __syncthreads();
        // GEMM2: k = u @ W2^T + b2
        do_gemm(g_W2p, gacc);
        __syncthreads();                      // u reads complete
        const float cs = (s == 2) ? 1.0f : 0.5f;
#pragma unroll
        for (int fm = 0; fm < 2; ++fm) {
            float dtf[4];
#pragma unroll
            for (int r = 0; r < 4; ++r) {
                const int m = m0 + fm * 16 + lq * 4 + r;
                const float2 tv = *(const float2*)&ts[2 * m];
                dtf[r] = tv.y - tv.x;
            }
#pragma unroll
            for (int fn = 0; fn < 4; ++fn)
#pragma unroll
                for (int r = 0; r < 4; ++r) {
                    const int row = fm * 16 + lq * 4 + r;
                    const int col = nb + fn * 16 + l15;
                    const float kv = gacc[fm][fn][r] + b2v[fn];
                    const size_t idx = (size_t)(m0 + row) * HSZ + col;
                    // rk accumulator lives in out_ht (fp32, thread-owned)
                    if (s == 0)      out_ht[idx] = kv;
                    else if (s < 3)  out_ht[idx] += 2.0f * kv;
                    const int off = row * 1024 + ((col * 2) ^ ((row & 7) << 4));
                    const float h2 = bf2f(*(const unsigned short*)((const char*)sH + off));
                    if (s < 3) {
                        *(unsigned short*)((char*)sU + off) = f2bf(h2 + cs * dtf[r] * kv);
                    } else {
                        out_ht[idx] = h2 + dtf[r] * (1.0f / 6.0f) * (out_ht[idx] + kv);
                    }
                }
        }
        if (s < 3) __syncthreads();
    }
}

extern "C" void kernel_launch(void* const* d_in, const int* in_sizes, int n_in,
                              void* d_out, int out_size, void* d_ws, size_t ws_size,
                              hipStream_t stream) {
    const float* x   = (const float*)d_in[0];
    const float* h0  = (const float*)d_in[1];
    const float* c0  = (const float*)d_in[2];
    const float* ts  = (const float*)d_in[3];
    const float* Wih = (const float*)d_in[4];
    const float* Whh = (const float*)d_in[5];
    const float* bih = (const float*)d_in[6];
    const float* bhh = (const float*)d_in[7];
    const float* W1  = (const float*)d_in[8];
    const float* b1  = (const float*)d_in[9];
    const float* W2  = (const float*)d_in[10];
    const float* b2  = (const float*)d_in[11];

    float* out_ht = (float*)d_out;
    float* out_c  = out_ht + (size_t)BATCH * HSZ;

    dim3 blk(256);
    conv_kernel<0><<<2048, blk, 0, stream>>>(x,   BATCH * ISZ / 4, 6, ISZ, 0);
    conv_kernel<1><<<2048, blk, 0, stream>>>(h0,  BATCH * HSZ / 4, 7, HSZ, 0);
    conv_kernel<2><<<256,  blk, 0, stream>>>(Wih, 2048 * 256 / 4,  6, KC, 0);
    conv_kernel<2><<<256,  blk, 0, stream>>>(Whh, 2048 * 512 / 4,  7, KC, 256);
    conv_fragW<0><<<128,  blk, 0, stream>>>(W1);
    conv_fragW<1><<<128,  blk, 0, stream>>>(W2);

    dim3 gcell(BATCH / 128 * 16);  // 4096 blocks: 16 n-chunks x 256 m-panels

    cell_kernel<0><<<gcell, blk, 0, stream>>>(bih, bhh, c0,    out_c);
    cell_kernel<1><<<gcell, blk, 0, stream>>>(bih, bhh, out_c, out_c);

    rk_fused_kernel<<<BATCH / 32, 512, 0, stream>>>(ts, b1, b2, out_ht);
}

// Round 17
// 819.579 us; speedup vs baseline: 1.4383x; 1.4383x over previous
//
#include <hip/hip_runtime.h>
#include <math.h>

#define BATCH 32768
#define ISZ   256
#define HSZ   512
#define KC    768   // cell GEMM K = ISZ + HSZ

typedef __attribute__((ext_vector_type(8))) short bf16x8;
typedef __attribute__((ext_vector_type(4))) float f32x4;

// bf16 activation / weight buffers (static to avoid ws_size dependence)
static __device__ unsigned short g_xbf[(size_t)BATCH * ISZ];   // x in bf16
static __device__ unsigned short g_ha [(size_t)BATCH * HSZ];   // h0 (bf16)
static __device__ unsigned short g_hb [(size_t)BATCH * HSZ];   // h1 (bf16)
static __device__ float          g_h2f[(size_t)BATCH * HSZ];   // new_h fp32
static __device__ unsigned short g_xw [(size_t)BATCH * 2048];  // x@Wih^T, per-thread-tile layout
static __device__ unsigned short g_Wc [2048 * KC];             // [Wih | Whh] bf16 [2048][768]
static __device__ unsigned short g_W1p[HSZ * HSZ];             // W1 in MFMA-fragment order
static __device__ unsigned short g_W2p[HSZ * HSZ];             // W2 in MFMA-fragment order

__device__ __forceinline__ unsigned short f2bf(float f) {
    unsigned int u = __float_as_uint(f);
    u += 0x7fff + ((u >> 16) & 1);   // RNE
    return (unsigned short)(u >> 16);
}
__device__ __forceinline__ float bf2f(unsigned short s) {
    return __uint_as_float((unsigned int)s << 16);
}
__device__ __forceinline__ float fsigm(float x) { return 1.0f / (1.0f + __expf(-x)); }
__device__ __forceinline__ float ftanh(float x) { return 1.0f - 2.0f / (__expf(2.0f * x) + 1.0f); }

__device__ __forceinline__ void gload16(const void* g, void* l) {
    __builtin_amdgcn_global_load_lds(
        (const __attribute__((address_space(1))) unsigned int*)g,
        (__attribute__((address_space(3))) unsigned int*)l, 16, 0, 0);
}

// ---------------------------------------------------------------------------
// fp32 -> bf16 conversion (float4-vectorized, row restride for Wih|Whh concat)
// DST: 0=g_xbf 1=g_ha 2=g_Wc
// ---------------------------------------------------------------------------
template <int DST>
__global__ __launch_bounds__(256) void conv_kernel(
    const float* __restrict__ src, int nv, int w4shift, int dstride, int doff)
{
    unsigned short* __restrict__ dst = DST == 0 ? g_xbf : DST == 1 ? g_ha : g_Wc;
    int i = blockIdx.x * 256 + threadIdx.x;
    const int gs = gridDim.x * 256;
    for (; i < nv; i += gs) {
        const int r = i >> w4shift;
        const int c = i & ((1 << w4shift) - 1);
        const float4 v = ((const float4*)src)[i];
        ushort4 o;
        o.x = f2bf(v.x); o.y = f2bf(v.y); o.z = f2bf(v.z); o.w = f2bf(v.w);
        *(ushort4*)&dst[(size_t)r * dstride + doff + c * 4] = o;
    }
}

// ---------------------------------------------------------------------------
// W1/W2 -> MFMA fragment order: chunk c = fb*1024 + st*64 + lq*16 + l15:
//   W'[c*8 + e] = W[fb*16+l15][st*32 + lq*8 + e]
// Fragment (fb, st) for lane l contiguous at W' + (fb*16+st)*512 + l*8 (1KB).
// ---------------------------------------------------------------------------
template <int DST>   // 0 -> g_W1p, 1 -> g_W2p
__global__ __launch_bounds__(256) void conv_fragW(const float* __restrict__ src)
{
    unsigned short* __restrict__ dst = DST == 0 ? g_W1p : g_W2p;
    const int c = blockIdx.x * 256 + threadIdx.x;   // 32768 chunks
    const int l15 = c & 15, lq = (c >> 4) & 3, st = (c >> 6) & 15, fb = c >> 10;
    const int n = fb * 16 + l15;
    const int k = st * 32 + lq * 8;
    const float4 v0 = *(const float4*)&src[(size_t)n * HSZ + k];
    const float4 v1 = *(const float4*)&src[(size_t)n * HSZ + k + 4];
    unsigned short o[8] = {f2bf(v0.x), f2bf(v0.y), f2bf(v0.z), f2bf(v0.w),
                           f2bf(v1.x), f2bf(v1.y), f2bf(v1.z), f2bf(v1.w)};
    *(bf16x8*)&dst[(size_t)c * 8] = *(bf16x8*)o;
}

// ---------------------------------------------------------------------------
// xW = x @ Wih^T precompute (shared by both cells). Same 128x128-vtile grid,
// same XCD swizzle, same thread mapping as cell_kernel -> per-thread acc tile
// is stored contiguously (64 bf16 = 128B/thread, coalesced) and read back by
// the cells in the identical layout. K=256 (4 K-tiles).
// ---------------------------------------------------------------------------
__global__ __launch_bounds__(256) void xw_kernel()
{
    constexpr int NKT = 4;
    constexpr int NCH = 16;

    __shared__ __align__(16) unsigned short As[128 * 64];
    __shared__ __align__(16) unsigned short Bs[128 * 64];

    const int orig = blockIdx.x;
    const int q = gridDim.x >> 3;
    const int wg = (orig & 7) * q + (orig >> 3);
    const int nbc = wg % NCH;
    const int mBase = (wg / NCH) * 128;

    const int tid  = threadIdx.x;
    const int lane = tid & 63;
    const int wid  = tid >> 6;
    const int wr   = wid >> 1, wc = wid & 1;
    const int l15  = lane & 15, lq = lane >> 4;

    const int arow = tid >> 3, ch = tid & 7;
    int bgrow[4];
#pragma unroll
    for (int j = 0; j < 4; ++j) {
        const int vr = j * 32 + arow;
        const int g    = (vr >> 4) & 3;
        const int jcol = nbc * 32 + (vr >> 6) * 16 + (vr & 15);
        bgrow[j] = g * 512 + jcol;
    }

    f32x4 acc[4][4];
#pragma unroll
    for (int fm = 0; fm < 4; ++fm)
#pragma unroll
        for (int fn = 0; fn < 4; ++fn) acc[fm][fn] = (f32x4){0.f, 0.f, 0.f, 0.f};

    for (int kt = 0; kt < NKT; ++kt) {
        const int k0 = kt * 64;
#pragma unroll
        for (int j = 0; j < 4; ++j) {
            const int row = j * 32 + arow;
            const unsigned short* ga = g_xbf + (size_t)(mBase + row) * ISZ + k0 + ch * 8;
            gload16(ga, (char*)As + j * 4096 + wid * 1024);
            const unsigned short* gb = g_Wc + (size_t)bgrow[j] * KC + k0 + ch * 8;
            gload16(gb, (char*)Bs + j * 4096 + wid * 1024);
        }
        __syncthreads();
#pragma unroll
        for (int kk = 0; kk < 2; ++kk) {
            bf16x8 a[4], b[4];
#pragma unroll
            for (int f = 0; f < 4; ++f) {
                const int rowA = wr * 64 + f * 16 + l15;
                a[f] = *(const bf16x8*)((const char*)As + rowA * 128 + kk * 64 + lq * 16);
                const int rowB = wc * 64 + f * 16 + l15;
                b[f] = *(const bf16x8*)((const char*)Bs + rowB * 128 + kk * 64 + lq * 16);
            }
#pragma unroll
            for (int fm = 0; fm < 4; ++fm)
#pragma unroll
                for (int fn = 0; fn < 4; ++fn)
                    acc[fm][fn] = __builtin_amdgcn_mfma_f32_16x16x32_bf16(
                        a[fm], b[fn], acc[fm][fn], 0, 0, 0);
        }
        __syncthreads();
    }

    unsigned short buf[64];
#pragma unroll
    for (int fm = 0; fm < 4; ++fm)
#pragma unroll
        for (int fn = 0; fn < 4; ++fn)
#pragma unroll
            for (int r = 0; r < 4; ++r)
                buf[(fm * 4 + fn) * 4 + r] = f2bf(acc[fm][fn][r]);
    unsigned short* dst = g_xw + ((size_t)wg * 256 + tid) * 64;
#pragma unroll
    for (int i = 0; i < 8; ++i)
        ((bf16x8*)dst)[i] = ((const bf16x8*)buf)[i];
}

// ---------------------------------------------------------------------------
// LSTM cell MFMA GEMM, SINGLE-buffered (R15-proven structure) but K=512 only
// (h @ Whh^T); the x @ Wih^T part comes pre-computed from g_xw (same grid,
// same swizzle, same thread mapping -> contiguous 128B/thread read).
// MODE 0: h1 -> g_hb (bf16).  MODE 1: h2 -> g_h2f (fp32).
// ---------------------------------------------------------------------------
template <int MODE>
__global__ __launch_bounds__(256) void cell_kernel(
    const float* __restrict__ bih, const float* __restrict__ bhh,
    const float* __restrict__ c_in, float* __restrict__ c_out)
{
    constexpr int NKT = HSZ / 64;   // 8
    constexpr int NCH = 16;

    __shared__ __align__(16) unsigned short As[128 * 64];
    __shared__ __align__(16) unsigned short Bs[128 * 64];

    const int orig = blockIdx.x;
    const int q = gridDim.x >> 3;
    const int wg = (orig & 7) * q + (orig >> 3);
    const int nbc = wg % NCH;
    const int mBase = (wg / NCH) * 128;

    const int tid  = threadIdx.x;
    const int lane = tid & 63;
    const int wid  = tid >> 6;
    const int wr   = wid >> 1, wc = wid & 1;
    const int l15  = lane & 15, lq = lane >> 4;

    const unsigned short* __restrict__ Ah = (MODE == 0) ? g_ha : g_hb;

    const int arow = tid >> 3, ch = tid & 7;
    int bgrow[4];
#pragma unroll
    for (int j = 0; j < 4; ++j) {
        const int vr = j * 32 + arow;
        const int g    = (vr >> 4) & 3;
        const int jcol = nbc * 32 + (vr >> 6) * 16 + (vr & 15);
        bgrow[j] = g * 512 + jcol;
    }

    f32x4 acc[4][4];
#pragma unroll
    for (int fm = 0; fm < 4; ++fm)
#pragma unroll
        for (int fn = 0; fn < 4; ++fn) acc[fm][fn] = (f32x4){0.f, 0.f, 0.f, 0.f};

    for (int kt = 0; kt < NKT; ++kt) {
        const int k0 = kt * 64;
#pragma unroll
        for (int j = 0; j < 4; ++j) {
            const int row = j * 32 + arow;
            const unsigned short* ga = Ah + (size_t)(mBase + row) * HSZ + k0 + ch * 8;
            gload16(ga, (char*)As + j * 4096 + wid * 1024);
            const unsigned short* gb = g_Wc + (size_t)bgrow[j] * KC + 256 + k0 + ch * 8;
            gload16(gb, (char*)Bs + j * 4096 + wid * 1024);
        }
        __syncthreads();
#pragma unroll
        for (int kk = 0; kk < 2; ++kk) {
            bf16x8 a[4], b[4];
#pragma unroll
            for (int f = 0; f < 4; ++f) {
                const int rowA = wr * 64 + f * 16 + l15;
                a[f] = *(const bf16x8*)((const char*)As + rowA * 128 + kk * 64 + lq * 16);
                const int rowB = wc * 64 + f * 16 + l15;
                b[f] = *(const bf16x8*)((const char*)Bs + rowB * 128 + kk * 64 + lq * 16);
            }
#pragma unroll
            for (int fm = 0; fm < 4; ++fm)
#pragma unroll
                for (int fn = 0; fn < 4; ++fn)
                    acc[fm][fn] = __builtin_amdgcn_mfma_f32_16x16x32_bf16(
                        a[fm], b[fn], acc[fm][fn], 0, 0, 0);
        }
        __syncthreads();
    }

    // read back the precomputed x@Wih^T tile (identical layout)
    unsigned short xwb[64];
    {
        const unsigned short* src = g_xw + ((size_t)wg * 256 + tid) * 64;
#pragma unroll
        for (int i = 0; i < 8; ++i)
            ((bf16x8*)xwb)[i] = ((const bf16x8*)src)[i];
    }

    const int j = nbc * 32 + wc * 16 + l15;
    float bsum[4];
#pragma unroll
    for (int g = 0; g < 4; ++g) bsum[g] = bih[g * 512 + j] + bhh[g * 512 + j];
#pragma unroll
    for (int fm = 0; fm < 4; ++fm) {
#pragma unroll
        for (int r = 0; r < 4; ++r) {
            const int m = mBase + wr * 64 + fm * 16 + lq * 4 + r;
            const size_t idx = (size_t)m * HSZ + j;
            const float ig = fsigm(acc[fm][0][r] + bf2f(xwb[(fm * 4 + 0) * 4 + r]) + bsum[0]);
            const float fg = fsigm(acc[fm][1][r] + bf2f(xwb[(fm * 4 + 1) * 4 + r]) + bsum[1]);
            const float gg = ftanh(acc[fm][2][r] + bf2f(xwb[(fm * 4 + 2) * 4 + r]) + bsum[2]);
            const float og = fsigm(acc[fm][3][r] + bf2f(xwb[(fm * 4 + 3) * 4 + r]) + bsum[3]);
            const float cnew = fg * c_in[idx] + ig * gg;
            const float hnew = og * ftanh(cnew);
            c_out[idx] = cnew;
            if constexpr (MODE == 0) g_hb[idx] = f2bf(hnew);
            else                     g_h2f[idx] = hnew;
        }
    }
}

// ---------------------------------------------------------------------------
// Fully-fused RK4 — EXACT R11/R15 version (proven 325us, VGPR 128, no spill).
// Block = 32 rows x 512 threads (8 waves), wave owns 32x64 (2m x 4n frags).
// Pipelined do_gemm with static b0/b1 full-step prefetch + sched_barrier.
// LDS: sU 32KB (htmp/u, XOR-swizzled) + sH 32KB (h2 bf16).
// ---------------------------------------------------------------------------
__global__ __launch_bounds__(512, 1) void rk_fused_kernel(
    const float* __restrict__ ts, const float* __restrict__ b1,
    const float* __restrict__ b2, float* __restrict__ out_ht)
{
    __shared__ __align__(16) unsigned short sU[32 * 512];   // 32 KB
    __shared__ __align__(16) unsigned short sH[32 * 512];   // 32 KB

    const int tid = threadIdx.x, lane = tid & 63;
    const int w = tid >> 6;                  // wave -> 64-col chunk
    const int l15 = lane & 15, lq = lane >> 4;
    const int nb = w * 64;
    const int m0 = blockIdx.x * 32;

    float b1v[4], b2v[4];
#pragma unroll
    for (int fn = 0; fn < 4; ++fn) {
        b1v[fn] = b1[nb + fn * 16 + l15];
        b2v[fn] = b2[nb + fn * 16 + l15];
    }

    // init: coalesced float4 read of h2, seed sU (htmp) and sH (h2 bf16)
    {
        const float4* __restrict__ src = (const float4*)(g_h2f + (size_t)m0 * HSZ);
#pragma unroll
        for (int i = 0; i < 8; ++i) {
            const int flat = i * 512 + tid;       // float4 index in 32x128
            const int row = flat >> 7;
            const int c4 = flat & 127;
            const float4 v = src[flat];
            ushort4 o;
            o.x = f2bf(v.x); o.y = f2bf(v.y); o.z = f2bf(v.z); o.w = f2bf(v.w);
            const int off = row * 1024 + ((c4 * 8) ^ ((row & 7) << 4));
            *(ushort4*)((char*)sU + off) = o;
            *(ushort4*)((char*)sH + off) = o;
        }
    }
    __syncthreads();

    f32x4 rk[2][4];
#pragma unroll
    for (int fm = 0; fm < 2; ++fm)
#pragma unroll
        for (int fn = 0; fn < 4; ++fn) rk[fm][fn] = (f32x4){0.f, 0.f, 0.f, 0.f};

    // fragment loaders
    auto loadB = [&](bf16x8 (&bb)[4], const unsigned short* __restrict__ Wp, int st) {
#pragma unroll
        for (int f = 0; f < 4; ++f)
            bb[f] = *(const bf16x8*)(Wp + (size_t)(((w * 4 + f) * 16 + st) * 512 + lane * 8));
    };
    auto loadA = [&](bf16x8 (&aa)[2], int st) {
#pragma unroll
        for (int f = 0; f < 2; ++f) {
            const int row = f * 16 + l15;
            aa[f] = *(const bf16x8*)((const char*)sU + row * 1024 +
                                     ((st * 64 + lq * 16) ^ ((l15 & 7) << 4)));
        }
    };

    auto do_gemm = [&](const unsigned short* __restrict__ Wp, f32x4 (&gacc)[2][4]) {
#pragma unroll
        for (int fm = 0; fm < 2; ++fm)
#pragma unroll
            for (int fn = 0; fn < 4; ++fn) gacc[fm][fn] = (f32x4){0.f, 0.f, 0.f, 0.f};
        bf16x8 b0[4], b1f[4], a[2];
        loadB(b0, Wp, 0);
#pragma unroll 1
        for (int st = 0; st < 16; st += 2) {
            loadB(b1f, Wp, st + 1);
            loadA(a, st);
#pragma unroll
            for (int fm = 0; fm < 2; ++fm)
#pragma unroll
                for (int fn = 0; fn < 4; ++fn)
                    gacc[fm][fn] = __builtin_amdgcn_mfma_f32_16x16x32_bf16(
                        a[fm], b0[fn], gacc[fm][fn], 0, 0, 0);
            __builtin_amdgcn_sched_barrier(0);
            if (st + 2 < 16) loadB(b0, Wp, st + 2);
            loadA(a, st + 1);
#pragma unroll
            for (int fm = 0; fm < 2; ++fm)
#pragma unroll
                for (int fn = 0; fn < 4; ++fn)
                    gacc[fm][fn] = __builtin_amdgcn_mfma_f32_16x16x32_bf16(
                        a[fm], b1f[fn], gacc[fm][fn], 0, 0, 0);
            __builtin_amdgcn_sched_barrier(0);
        }
    };

#pragma unroll 1
    for (int s = 0; s < 4; ++s) {
        f32x4 gacc[2][4];
        // GEMM1: u = tanh(htmp @ W1^T + b1)
        do_gemm(g_W1p, gacc);
        __syncthreads();                      // htmp reads complete
#pragma unroll
        for (int fm = 0; fm < 2; ++fm)
#pragma unroll
            for (int fn = 0; fn < 4; ++fn)
#pragma unroll
                for (int r = 0; r < 4; ++r) {
                    const int row = fm * 16 + lq * 4 + r;
                    const int col = nb + fn * 16 + l15;
                    *(unsigned short*)((char*)sU + row * 1024 +
                                       ((col * 2) ^ ((row & 7) << 4))) =
                        f2bf(ftanh(gacc[fm][fn][r] + b1v[fn]));
                }
        __syncthreads();
        // GEMM2: k = u @ W2^T + b2
        do_gemm(g_W2p, gacc);
        __syncthreads();                      // u reads complete
        const float wk = (s == 1 || s == 2) ? 2.0f : 1.0f;
        const float cs = (s == 2) ? 1.0f : 0.5f;
#pragma unroll
        for (int fm = 0; fm < 2; ++fm) {
            float dtf[4];
#pragma unroll
            for (int r = 0; r < 4; ++r) {
                const int m = m0 + fm * 16 + lq * 4 + r;
                const float2 tv = *(const float2*)&ts[2 * m];
                dtf[r] = tv.y - tv.x;
            }
#pragma unroll
            for (int fn = 0; fn < 4; ++fn)
#pragma unroll
                for (int r = 0; r < 4; ++r) {
                    const int row = fm * 16 + lq * 4 + r;
                    const int col = nb + fn * 16 + l15;
                    const float kv = gacc[fm][fn][r] + b2v[fn];
                    rk[fm][fn][r] += wk * kv;
                    if (s < 3) {
                        const int off = row * 1024 + ((col * 2) ^ ((row & 7) << 4));
                        const float h2 = bf2f(*(const unsigned short*)((const char*)sH + off));
                        *(unsigned short*)((char*)sU + off) = f2bf(h2 + cs * dtf[r] * kv);
                    } else {
                        const size_t idx = (size_t)(m0 + row) * HSZ + col;
                        out_ht[idx] = g_h2f[idx] + dtf[r] * (1.0f / 6.0f) * rk[fm][fn][r];
                    }
                }
        }
        if (s < 3) __syncthreads();
    }
}

extern "C" void kernel_launch(void* const* d_in, const int* in_sizes, int n_in,
                              void* d_out, int out_size, void* d_ws, size_t ws_size,
                              hipStream_t stream) {
    const float* x   = (const float*)d_in[0];
    const float* h0  = (const float*)d_in[1];
    const float* c0  = (const float*)d_in[2];
    const float* ts  = (const float*)d_in[3];
    const float* Wih = (const float*)d_in[4];
    const float* Whh = (const float*)d_in[5];
    const float* bih = (const float*)d_in[6];
    const float* bhh = (const float*)d_in[7];
    const float* W1  = (const float*)d_in[8];
    const float* b1  = (const float*)d_in[9];
    const float* W2  = (const float*)d_in[10];
    const float* b2  = (const float*)d_in[11];

    float* out_ht = (float*)d_out;
    float* out_c  = out_ht + (size_t)BATCH * HSZ;

    dim3 blk(256);
    conv_kernel<0><<<2048, blk, 0, stream>>>(x,   BATCH * ISZ / 4, 6, ISZ, 0);
    conv_kernel<1><<<2048, blk, 0, stream>>>(h0,  BATCH * HSZ / 4, 7, HSZ, 0);
    conv_kernel<2><<<256,  blk, 0, stream>>>(Wih, 2048 * 256 / 4,  6, KC, 0);
    conv_kernel<2><<<256,  blk, 0, stream>>>(Whh, 2048 * 512 / 4,  7, KC, 256);
    conv_fragW<0><<<128,  blk, 0, stream>>>(W1);
    conv_fragW<1><<<128,  blk, 0, stream>>>(W2);

    dim3 gcell(BATCH / 128 * 16);  // 4096 blocks: 16 n-chunks x 256 m-panels

    xw_kernel<<<gcell, blk, 0, stream>>>();
    cell_kernel<0><<<gcell, blk, 0, stream>>>(bih, bhh, c0,    out_c);
    cell_kernel<1><<<gcell, blk, 0, stream>>>(bih, bhh, out_c, out_c);

    rk_fused_kernel<<<BATCH / 32, 512, 0, stream>>>(ts, b1, b2, out_ht);
}

// Round 18
// 731.524 us; speedup vs baseline: 1.6115x; 1.1204x over previous
//
#include <hip/hip_runtime.h>
#include <math.h>

#define BATCH 32768
#define ISZ   256
#define HSZ   512
#define KC    768   // cell GEMM K = ISZ + HSZ

typedef __attribute__((ext_vector_type(8))) short bf16x8;
typedef __attribute__((ext_vector_type(4))) float f32x4;

// bf16 activation / weight buffers (static to avoid ws_size dependence)
static __device__ unsigned short g_xbf[(size_t)BATCH * ISZ];   // x in bf16
static __device__ unsigned short g_ha [(size_t)BATCH * HSZ];   // h0 (bf16)
static __device__ unsigned short g_hb [(size_t)BATCH * HSZ];   // h1 (bf16)
static __device__ float          g_h2f[(size_t)BATCH * HSZ];   // new_h fp32
static __device__ unsigned short g_Wc [2048 * KC];             // [Wih | Whh] bf16 [2048][768]
static __device__ unsigned short g_W1p[HSZ * HSZ];             // W1 in MFMA-fragment order
static __device__ unsigned short g_W2p[HSZ * HSZ];             // W2 in MFMA-fragment order

__device__ __forceinline__ unsigned short f2bf(float f) {
    unsigned int u = __float_as_uint(f);
    u += 0x7fff + ((u >> 16) & 1);   // RNE
    return (unsigned short)(u >> 16);
}
__device__ __forceinline__ float bf2f(unsigned short s) {
    return __uint_as_float((unsigned int)s << 16);
}
__device__ __forceinline__ float fsigm(float x) { return 1.0f / (1.0f + __expf(-x)); }
__device__ __forceinline__ float ftanh(float x) { return 1.0f - 2.0f / (__expf(2.0f * x) + 1.0f); }

__device__ __forceinline__ void gload16(const void* g, void* l) {
    __builtin_amdgcn_global_load_lds(
        (const __attribute__((address_space(1))) unsigned int*)g,
        (__attribute__((address_space(3))) unsigned int*)l, 16, 0, 0);
}

__device__ __forceinline__ ushort4 cvt4(float4 v) {
    ushort4 o;
    o.x = f2bf(v.x); o.y = f2bf(v.y); o.z = f2bf(v.z); o.w = f2bf(v.w);
    return o;
}

// ---------------------------------------------------------------------------
// Fused input conversion: x (flat) + h0 (flat). Both destinations are exactly
// contiguous, so this is a straight copy-convert. Blocks [0,2048): x,
// [2048,4096): h0, each grid-strided.
// ---------------------------------------------------------------------------
__global__ __launch_bounds__(256) void conv_inputs_kernel(
    const float* __restrict__ x, const float* __restrict__ h0)
{
    const int b = blockIdx.x;
    if (b < 2048) {
        const int nv = BATCH * ISZ / 4;
        for (int i = b * 256 + threadIdx.x; i < nv; i += 2048 * 256)
            *(ushort4*)&g_xbf[(size_t)i * 4] = cvt4(((const float4*)x)[i]);
    } else {
        const int nv = BATCH * HSZ / 4;
        for (int i = (b - 2048) * 256 + threadIdx.x; i < nv; i += 2048 * 256)
            *(ushort4*)&g_ha[(size_t)i * 4] = cvt4(((const float4*)h0)[i]);
    }
}

// ---------------------------------------------------------------------------
// Fused weight prep (one launch, 1792 blocks, exact coverage):
//  [0,512):    Wih -> g_Wc cols [0,256)   (restride to [2048][768])
//  [512,1536): Whh -> g_Wc cols [256,768)
//  [1536,1664): W1 -> g_W1p MFMA-fragment order
//  [1664,1792): W2 -> g_W2p MFMA-fragment order
// Fragment order: chunk c = fb*1024 + st*64 + lq*16 + l15:
//   W'[c*8 + e] = W[fb*16+l15][st*32 + lq*8 + e]
// ---------------------------------------------------------------------------
__global__ __launch_bounds__(256) void conv_weights_kernel(
    const float* __restrict__ Wih, const float* __restrict__ Whh,
    const float* __restrict__ W1, const float* __restrict__ W2)
{
    const int b = blockIdx.x;
    if (b < 512) {
        const int i = b * 256 + threadIdx.x;        // 131072 f4 chunks
        const int r = i >> 6, c = i & 63;
        *(ushort4*)&g_Wc[(size_t)r * KC + c * 4] = cvt4(((const float4*)Wih)[i]);
    } else if (b < 1536) {
        const int i = (b - 512) * 256 + threadIdx.x; // 262144 f4 chunks
        const int r = i >> 7, c = i & 127;
        *(ushort4*)&g_Wc[(size_t)r * KC + 256 + c * 4] = cvt4(((const float4*)Whh)[i]);
    } else {
        const bool w2 = (b >= 1664);
        const float* __restrict__ src = w2 ? W2 : W1;
        unsigned short* __restrict__ dst = w2 ? g_W2p : g_W1p;
        const int c = (b - (w2 ? 1664 : 1536)) * 256 + threadIdx.x;  // 32768 chunks
        const int l15 = c & 15, lq = (c >> 4) & 3, st = (c >> 6) & 15, fb = c >> 10;
        const int n = fb * 16 + l15;
        const int k = st * 32 + lq * 8;
        const float4 v0 = *(const float4*)&src[(size_t)n * HSZ + k];
        const float4 v1 = *(const float4*)&src[(size_t)n * HSZ + k + 4];
        unsigned short o[8] = {f2bf(v0.x), f2bf(v0.y), f2bf(v0.z), f2bf(v0.w),
                               f2bf(v1.x), f2bf(v1.y), f2bf(v1.z), f2bf(v1.w)};
        *(bf16x8*)&dst[(size_t)c * 8] = *(bf16x8*)o;
    }
}

// ---------------------------------------------------------------------------
// LSTM cell MFMA GEMM, SINGLE-buffered (m97-style, R15-proven): 128x128 tile,
// BK=64, 4 waves, 32KB LDS -> high occupancy, cross-block implicit overlap.
// 1D grid, bijective XCD swizzle, n-chunk fastest (A-panel L2 reuse).
// MODE 0: h1 -> g_hb (bf16).  MODE 1: h2 -> g_h2f (fp32).
// ---------------------------------------------------------------------------
template <int MODE>
__global__ __launch_bounds__(256) void cell_kernel(
    const float* __restrict__ bih, const float* __restrict__ bhh,
    const float* __restrict__ c_in, float* __restrict__ c_out)
{
    constexpr int NKT = KC / 64;   // 12
    constexpr int NCH = 16;

    __shared__ __align__(16) unsigned short As[128 * 64];
    __shared__ __align__(16) unsigned short Bs[128 * 64];

    const int orig = blockIdx.x;
    const int q = gridDim.x >> 3;
    const int wg = (orig & 7) * q + (orig >> 3);
    const int nbc = wg % NCH;
    const int mBase = (wg / NCH) * 128;

    const int tid  = threadIdx.x;
    const int lane = tid & 63;
    const int wid  = tid >> 6;
    const int wr   = wid >> 1, wc = wid & 1;
    const int l15  = lane & 15, lq = lane >> 4;

    const unsigned short* __restrict__ Ah = (MODE == 0) ? g_ha : g_hb;

    const int arow = tid >> 3, ch = tid & 7;
    int bgrow[4];
#pragma unroll
    for (int j = 0; j < 4; ++j) {
        const int vr = j * 32 + arow;
        const int g    = (vr >> 4) & 3;
        const int jcol = nbc * 32 + (vr >> 6) * 16 + (vr & 15);
        bgrow[j] = g * 512 + jcol;
    }

    f32x4 acc[4][4];
#pragma unroll
    for (int fm = 0; fm < 4; ++fm)
#pragma unroll
        for (int fn = 0; fn < 4; ++fn) acc[fm][fn] = (f32x4){0.f, 0.f, 0.f, 0.f};

    for (int kt = 0; kt < NKT; ++kt) {
        const int k0 = kt * 64;
#pragma unroll
        for (int j = 0; j < 4; ++j) {
            const int row = j * 32 + arow;
            const unsigned short* ga = (k0 < 256)
                ? g_xbf + (size_t)(mBase + row) * ISZ + (k0       + ch * 8)
                : Ah    + (size_t)(mBase + row) * HSZ + (k0 - 256 + ch * 8);
            gload16(ga, (char*)As + j * 4096 + wid * 1024);
            const unsigned short* gb = g_Wc + (size_t)bgrow[j] * KC + k0 + ch * 8;
            gload16(gb, (char*)Bs + j * 4096 + wid * 1024);
        }
        __syncthreads();
#pragma unroll
        for (int kk = 0; kk < 2; ++kk) {
            bf16x8 a[4], b[4];
#pragma unroll
            for (int f = 0; f < 4; ++f) {
                const int rowA = wr * 64 + f * 16 + l15;
                a[f] = *(const bf16x8*)((const char*)As + rowA * 128 + kk * 64 + lq * 16);
                const int rowB = wc * 64 + f * 16 + l15;
                b[f] = *(const bf16x8*)((const char*)Bs + rowB * 128 + kk * 64 + lq * 16);
            }
#pragma unroll
            for (int fm = 0; fm < 4; ++fm)
#pragma unroll
                for (int fn = 0; fn < 4; ++fn)
                    acc[fm][fn] = __builtin_amdgcn_mfma_f32_16x16x32_bf16(
                        a[fm], b[fn], acc[fm][fn], 0, 0, 0);
        }
        __syncthreads();
    }

    const int j = nbc * 32 + wc * 16 + l15;
    float bsum[4];
#pragma unroll
    for (int g = 0; g < 4; ++g) bsum[g] = bih[g * 512 + j] + bhh[g * 512 + j];
#pragma unroll
    for (int fm = 0; fm < 4; ++fm) {
#pragma unroll
        for (int r = 0; r < 4; ++r) {
            const int m = mBase + wr * 64 + fm * 16 + lq * 4 + r;
            const size_t idx = (size_t)m * HSZ + j;
            const float ig = fsigm(acc[fm][0][r] + bsum[0]);
            const float fg = fsigm(acc[fm][1][r] + bsum[1]);
            const float gg = ftanh(acc[fm][2][r] + bsum[2]);
            const float og = fsigm(acc[fm][3][r] + bsum[3]);
            const float cnew = fg * c_in[idx] + ig * gg;
            const float hnew = og * ftanh(cnew);
            c_out[idx] = cnew;
            if constexpr (MODE == 0) g_hb[idx] = f2bf(hnew);
            else                     g_h2f[idx] = hnew;
        }
    }
}

// ---------------------------------------------------------------------------
// Fully-fused RK4 — EXACT R11/R15 version (proven 325us, VGPR 128, no spill).
// Block = 32 rows x 512 threads (8 waves), wave owns 32x64 (2m x 4n frags).
// Pipelined do_gemm with static b0/b1 full-step prefetch + sched_barrier.
// LDS: sU 32KB (htmp/u, XOR-swizzled) + sH 32KB (h2 bf16).
// ---------------------------------------------------------------------------
__global__ __launch_bounds__(512, 1) void rk_fused_kernel(
    const float* __restrict__ ts, const float* __restrict__ b1,
    const float* __restrict__ b2, float* __restrict__ out_ht)
{
    __shared__ __align__(16) unsigned short sU[32 * 512];   // 32 KB
    __shared__ __align__(16) unsigned short sH[32 * 512];   // 32 KB

    const int tid = threadIdx.x, lane = tid & 63;
    const int w = tid >> 6;                  // wave -> 64-col chunk
    const int l15 = lane & 15, lq = lane >> 4;
    const int nb = w * 64;
    const int m0 = blockIdx.x * 32;

    float b1v[4], b2v[4];
#pragma unroll
    for (int fn = 0; fn < 4; ++fn) {
        b1v[fn] = b1[nb + fn * 16 + l15];
        b2v[fn] = b2[nb + fn * 16 + l15];
    }

    // init: coalesced float4 read of h2, seed sU (htmp) and sH (h2 bf16)
    {
        const float4* __restrict__ src = (const float4*)(g_h2f + (size_t)m0 * HSZ);
#pragma unroll
        for (int i = 0; i < 8; ++i) {
            const int flat = i * 512 + tid;       // float4 index in 32x128
            const int row = flat >> 7;
            const int c4 = flat & 127;
            const float4 v = src[flat];
            ushort4 o = cvt4(v);
            const int off = row * 1024 + ((c4 * 8) ^ ((row & 7) << 4));
            *(ushort4*)((char*)sU + off) = o;
            *(ushort4*)((char*)sH + off) = o;
        }
    }
    __syncthreads();

    f32x4 rk[2][4];
#pragma unroll
    for (int fm = 0; fm < 2; ++fm)
#pragma unroll
        for (int fn = 0; fn < 4; ++fn) rk[fm][fn] = (f32x4){0.f, 0.f, 0.f, 0.f};

    // fragment loaders
    auto loadB = [&](bf16x8 (&bb)[4], const unsigned short* __restrict__ Wp, int st) {
#pragma unroll
        for (int f = 0; f < 4; ++f)
            bb[f] = *(const bf16x8*)(Wp + (size_t)(((w * 4 + f) * 16 + st) * 512 + lane * 8));
    };
    auto loadA = [&](bf16x8 (&aa)[2], int st) {
#pragma unroll
        for (int f = 0; f < 2; ++f) {
            const int row = f * 16 + l15;
            aa[f] = *(const bf16x8*)((const char*)sU + row * 1024 +
                                     ((st * 64 + lq * 16) ^ ((l15 & 7) << 4)));
        }
    };

    auto do_gemm = [&](const unsigned short* __restrict__ Wp, f32x4 (&gacc)[2][4]) {
#pragma unroll
        for (int fm = 0; fm < 2; ++fm)
#pragma unroll
            for (int fn = 0; fn < 4; ++fn) gacc[fm][fn] = (f32x4){0.f, 0.f, 0.f, 0.f};
        bf16x8 b0[4], b1f[4], a[2];
        loadB(b0, Wp, 0);
#pragma unroll 1
        for (int st = 0; st < 16; st += 2) {
            loadB(b1f, Wp, st + 1);
            loadA(a, st);
#pragma unroll
            for (int fm = 0; fm < 2; ++fm)
#pragma unroll
                for (int fn = 0; fn < 4; ++fn)
                    gacc[fm][fn] = __builtin_amdgcn_mfma_f32_16x16x32_bf16(
                        a[fm], b0[fn], gacc[fm][fn], 0, 0, 0);
            __builtin_amdgcn_sched_barrier(0);
            if (st + 2 < 16) loadB(b0, Wp, st + 2);
            loadA(a, st + 1);
#pragma unroll
            for (int fm = 0; fm < 2; ++fm)
#pragma unroll
                for (int fn = 0; fn < 4; ++fn)
                    gacc[fm][fn] = __builtin_amdgcn_mfma_f32_16x16x32_bf16(
                        a[fm], b1f[fn], gacc[fm][fn], 0, 0, 0);
            __builtin_amdgcn_sched_barrier(0);
        }
    };

#pragma unroll 1
    for (int s = 0; s < 4; ++s) {
        f32x4 gacc[2][4];
        // GEMM1: u = tanh(htmp @ W1^T + b1)
        do_gemm(g_W1p, gacc);
        __syncthreads();                      // htmp reads complete
#pragma unroll
        for (int fm = 0; fm < 2; ++fm)
#pragma unroll
            for (int fn = 0; fn < 4; ++fn)
#pragma unroll
                for (int r = 0; r < 4; ++r) {
                    const int row = fm * 16 + lq * 4 + r;
                    const int col = nb + fn * 16 + l15;
                    *(unsigned short*)((char*)sU + row * 1024 +
                                       ((col * 2) ^ ((row & 7) << 4))) =
                        f2bf(ftanh(gacc[fm][fn][r] + b1v[fn]));
                }
        __syncthreads();
        // GEMM2: k = u @ W2^T + b2
        do_gemm(g_W2p, gacc);
        __syncthreads();                      // u reads complete
        const float wk = (s == 1 || s == 2) ? 2.0f : 1.0f;
        const float cs = (s == 2) ? 1.0f : 0.5f;
#pragma unroll
        for (int fm = 0; fm < 2; ++fm) {
            float dtf[4];
#pragma unroll
            for (int r = 0; r < 4; ++r) {
                const int m = m0 + fm * 16 + lq * 4 + r;
                const float2 tv = *(const float2*)&ts[2 * m];
                dtf[r] = tv.y - tv.x;
            }
#pragma unroll
            for (int fn = 0; fn < 4; ++fn)
#pragma unroll
                for (int r = 0; r < 4; ++r) {
                    const int row = fm * 16 + lq * 4 + r;
                    const int col = nb + fn * 16 + l15;
                    const float kv = gacc[fm][fn][r] + b2v[fn];
                    rk[fm][fn][r] += wk * kv;
                    if (s < 3) {
                        const int off = row * 1024 + ((col * 2) ^ ((row & 7) << 4));
                        const float h2 = bf2f(*(const unsigned short*)((const char*)sH + off));
                        *(unsigned short*)((char*)sU + off) = f2bf(h2 + cs * dtf[r] * kv);
                    } else {
                        const size_t idx = (size_t)(m0 + row) * HSZ + col;
                        out_ht[idx] = g_h2f[idx] + dtf[r] * (1.0f / 6.0f) * rk[fm][fn][r];
                    }
                }
        }
        if (s < 3) __syncthreads();
    }
}

extern "C" void kernel_launch(void* const* d_in, const int* in_sizes, int n_in,
                              void* d_out, int out_size, void* d_ws, size_t ws_size,
                              hipStream_t stream) {
    const float* x   = (const float*)d_in[0];
    const float* h0  = (const float*)d_in[1];
    const float* c0  = (const float*)d_in[2];
    const float* ts  = (const float*)d_in[3];
    const float* Wih = (const float*)d_in[4];
    const float* Whh = (const float*)d_in[5];
    const float* bih = (const float*)d_in[6];
    const float* bhh = (const float*)d_in[7];
    const float* W1  = (const float*)d_in[8];
    const float* b1  = (const float*)d_in[9];
    const float* W2  = (const float*)d_in[10];
    const float* b2  = (const float*)d_in[11];

    float* out_ht = (float*)d_out;
    float* out_c  = out_ht + (size_t)BATCH * HSZ;

    dim3 blk(256);
    conv_inputs_kernel <<<4096, blk, 0, stream>>>(x, h0);
    conv_weights_kernel<<<1792, blk, 0, stream>>>(Wih, Whh, W1, W2);

    dim3 gcell(BATCH / 128 * 16);  // 4096 blocks: 16 n-chunks x 256 m-panels

    cell_kernel<0><<<gcell, blk, 0, stream>>>(bih, bhh, c0,    out_c);
    cell_kernel<1><<<gcell, blk, 0, stream>>>(bih, bhh, out_c, out_c);

    rk_fused_kernel<<<BATCH / 32, 512, 0, stream>>>(ts, b1, b2, out_ht);
}